// Round 14
// baseline (428.611 us; speedup 1.0000x reference)
//
#include <hip/hip_runtime.h>

// GSSelfAttn: B=2048 windows, N=144 tokens, D=180, H=6 heads, hd=30.
// R14: R11 base + register-resident P AND O via operand-swapped K=16 MFMAs.
//  - S C-layout == mfma_16x16x16 B-frag  -> PV reads P from REGISTERS
//  - PV(A=Vt,B=P) C-layout == proj A-frag -> O never touches LDS either
//  - 9x16 token tiles: no pad, no tail predication; rinv needs no shfl
//  - Wp repacked as K=16-tile b64 B-fragments; proj = 72x mfma_k16
// Head-paired iters, glds W prefetch, barrier-free epilogue retained from R11.
// LDS 129024: WB0/WB1 2x36864 | strips 9x2048 (Q-transpose only) | K[2] | Vt[2].

typedef __bf16 bf16_t;
typedef __bf16 bf16x8 __attribute__((ext_vector_type(8)));
typedef __bf16 bf16x4 __attribute__((ext_vector_type(4)));
typedef short s16x4 __attribute__((ext_vector_type(4)));
typedef float f32x4 __attribute__((ext_vector_type(4)));

#define MFMA16(a, b, c) __builtin_amdgcn_mfma_f32_16x16x32_bf16((a), (b), (c), 0, 0, 0)
#define MFMA_K16(a, b, c) __builtin_amdgcn_mfma_f32_16x16x16bf16_1k((a), (b), (c), 0, 0, 0)
#define GLDS16(g, l) __builtin_amdgcn_global_load_lds(                         \
    (const __attribute__((address_space(1))) void*)(g),                        \
    (__attribute__((address_space(3))) void*)(l), 16, 0, 0)

static __device__ __forceinline__ f32x4 fzero4() {
    f32x4 z; z[0] = 0.f; z[1] = 0.f; z[2] = 0.f; z[3] = 0.f; return z;
}
static __device__ __forceinline__ short f2bf(float f) {
    return __builtin_bit_cast(short, (__bf16)f);
}

// ---------------- pack kernel ----------------
// ws layout (bytes):
//   Wqkv  @ 0      : [h][kt6][nt6][lane64][j8] bf16      = 221184 B (Q cols *30^-.5*log2e)
//   Wp16  @ 221184 : [half2][kt12][nt6][lane64][j4] bf16 =  73728 B (K=16 B-frags:
//                    k=kt*16+(l>>4)*4+j, col=half*96+nt*16+(l&15))
//   BIASf @ 294912 : [h][wv9][nt9][lane64][r4] bf16      = 248832 B (S^T frag, *log2e)
//   bqkv  @ 543744 : [h][c96] fp32                       =   2304 B (Q part *scale*log2e)
__global__ void pack_kernel(const float* __restrict__ wq, const float* __restrict__ bq,
                            const float* __restrict__ wk, const float* __restrict__ bk,
                            const float* __restrict__ wv, const float* __restrict__ bv,
                            const float* __restrict__ wp, const float* __restrict__ bt,
                            bf16_t* __restrict__ Wqkv, bf16_t* __restrict__ Wp,
                            bf16_t* __restrict__ BIASf, float* __restrict__ bqkv)
{
    const int t = blockIdx.x * blockDim.x + threadIdx.x;
    const int stride = gridDim.x * blockDim.x;
    const float L2E = 1.4426950408889634f;
    const float qscale = 0.18257418583505536f * L2E;

    for (int i = t; i < 6 * 6 * 6 * 512; i += stride) {
        int j = i & 7, lane = (i >> 3) & 63;
        int f = i >> 9;               // [h][kt][nt]
        int nt = f % 6, kt = (f / 6) % 6, h = f / 36;
        int kin = kt * 32 + (lane >> 4) * 8 + j;
        int c = nt * 16 + (lane & 15);       // 0..95
        int sec = c >> 5, d = c & 31;
        float v = 0.f;
        if (kin < 180 && d < 30) {
            int col = h * 30 + d;
            if (sec == 0)      v = wq[kin * 180 + col] * qscale;
            else if (sec == 1) v = wk[kin * 180 + col];
            else               v = wv[kin * 180 + col];
        }
        Wqkv[i] = (bf16_t)v;
    }
    // Wp K=16-tile B-fragments, half-major
    for (int i = t; i < 2 * 12 * 6 * 256; i += stride) {
        int j = i & 3, lane = (i >> 2) & 63;
        int f = i >> 8;               // [half][kt][nt]
        int nt = f % 6, kt = (f / 6) % 12, half = f / 72;
        int k = kt * 16 + (lane >> 4) * 4 + j;   // 0..191 = h*32 + d
        int hh = k >> 5, d = k & 31;
        int cout = half * 96 + nt * 16 + (lane & 15);
        float v = 0.f;
        if (d < 30 && cout < 180) v = wp[(hh * 30 + d) * 180 + cout];
        Wp[i] = (bf16_t)v;
    }
    for (int i = t; i < 6 * 9 * 9 * 64; i += stride) {
        int lane = i & 63;
        int f = i >> 6;               // [h][wv][nt]
        int nt = f % 9, wvq = (f / 9) % 9, h = f / 81;
        int q = wvq * 16 + (lane & 15);
        int qi = q / 12, qj = q % 12;
        #pragma unroll
        for (int r = 0; r < 4; ++r) {
            int k = nt * 16 + (lane >> 4) * 4 + r;
            int ki = k / 12, kj = k % 12;
            int rel = (qi - ki + 11) * 23 + (qj - kj + 11);
            BIASf[i * 4 + r] = (bf16_t)(bt[rel * 6 + h] * L2E);
        }
    }
    for (int i = t; i < 576; i += stride) {
        int c = i % 96, h = i / 96;
        int sec = c >> 5, d = c & 31;
        float v = 0.f;
        if (d < 30) {
            if (sec == 0)      v = bq[h * 30 + d] * qscale;
            else if (sec == 1) v = bk[h * 30 + d];
            else               v = bv[h * 30 + d];
        }
        bqkv[i] = v;
    }
}

// ---------------- fused attention kernel ----------------
// block = 576 threads = 9 waves; wave wv owns M-strip rows [16wv, 16wv+16)
// LDS map (129024 B):
//   WB0   @ 0      : 36864 (even-head W; Wp half0 in last iter)
//   WB1   @ 36864  : 36864 (odd-head W; Wp half1 in last iter)
//   strips@ 73728  : 9 x 2048 (chunk0/chunk1 = Q transpose scratch h0/h1)
//   K[2]  @ 92160  : per-parity [144][32] bf16, swizzle ^((row&6)<<3)
//   Vt[2] @ 110592 : per-parity [32][144] bf16 stride 288, 64B-blks 0..3 swizzled
__global__ __launch_bounds__(576, 2)
void attn_kernel(const float* __restrict__ gs,
                 const bf16_t* __restrict__ Wqkv, const bf16_t* __restrict__ Wp,
                 const bf16_t* __restrict__ BIASf, const float* __restrict__ bqkv,
                 const float* __restrict__ bp, float* __restrict__ out)
{
    __shared__ __align__(16) unsigned char smem[129024];

    const int tid = threadIdx.x;
    const int lane = tid & 63;
    const int wv = tid >> 6;          // wave id = M-strip 0..8
    const int l15 = lane & 15;
    const int lg = lane >> 4;         // 0..3
    const int win = blockIdx.x;
    const float* __restrict__ gsw = gs + (size_t)win * 25920;

    constexpr int WB0     = 0;
    constexpr int WB1     = 36864;
    constexpr int ST_BASE = 73728;
    constexpr int K_BASE  = 92160;    // h0 parity 0; +9216 for h1
    constexpr int VT_BASE = 110592;

    // ---- prologue: async-stage W(0)->WB0, W(1)->WB1; load gs ----
    #pragma unroll
    for (int i = 0; i < 4; ++i) {
        const int base = wv * 64 + i * 576;
        GLDS16((const char*)Wqkv + (size_t)(base + lane) * 16, smem + WB0 + base * 16);
    }
    #pragma unroll
    for (int i = 0; i < 4; ++i) {
        const int base = wv * 64 + i * 576;
        GLDS16((const char*)Wqkv + 36864 + (size_t)(base + lane) * 16, smem + WB1 + base * 16);
    }

    bf16x8 xa[6];
    {
        const int row = wv * 16 + l15;
        const float4* __restrict__ g4 = (const float4*)(gsw + row * 180);
        #pragma unroll
        for (int kt = 0; kt < 6; ++kt) {
            const int c0 = kt * 32 + lg * 8;
            float4 lo = {0.f, 0.f, 0.f, 0.f}, hi = {0.f, 0.f, 0.f, 0.f};
            if (c0 + 4 <= 180) lo = g4[c0 >> 2];
            if (c0 + 8 <= 180) hi = g4[(c0 >> 2) + 1];
            bf16x8 v;
            v[0] = (bf16_t)lo.x; v[1] = (bf16_t)lo.y; v[2] = (bf16_t)lo.z; v[3] = (bf16_t)lo.w;
            v[4] = (bf16_t)hi.x; v[5] = (bf16_t)hi.y; v[6] = (bf16_t)hi.z; v[7] = (bf16_t)hi.w;
            xa[kt] = v;
        }
    }
    __syncthreads();                  // drains glds: W(0),W(1) staged

    s16x4 po[12];                     // O frags [head*2 + dblk] (proj A-frags, K=16)
    char* const pb = (char*)smem + ST_BASE + wv * 2048;   // wave-private scratch
    const int row0 = wv * 16 + lg * 4;

    auto qkv_scatter = [&](const int hh, const int wbofs, bf16_t* q8o) {
        const int KB = K_BASE + (hh & 1) * 9216;
        const int VB = VT_BASE + (hh & 1) * 9216;
        f32x4 acc[6];
        #pragma unroll
        for (int nt = 0; nt < 6; ++nt) acc[nt] = fzero4();
        __builtin_amdgcn_s_setprio(1);
        #pragma unroll
        for (int kt = 0; kt < 6; ++kt) {
            #pragma unroll
            for (int nt = 0; nt < 6; ++nt) {
                bf16x8 bw = *(const bf16x8*)(smem + wbofs + ((kt * 6 + nt) * 64 + lane) * 16);
                acc[nt] = MFMA16(xa[kt], bw, acc[nt]);
            }
        }
        __builtin_amdgcn_s_setprio(0);
        #pragma unroll
        for (int nt = 0; nt < 2; ++nt) {
            const float bias = bqkv[hh * 96 + nt * 16 + l15];
            #pragma unroll
            for (int r = 0; r < 4; ++r)
                q8o[nt * 4 + r] = (bf16_t)(acc[nt][r] + bias);
        }
        #pragma unroll
        for (int nt = 2; nt < 4; ++nt) {
            const float bias = bqkv[hh * 96 + nt * 16 + l15];
            const int d32 = ((nt & 1) << 4) + l15;
            #pragma unroll
            for (int r = 0; r < 4; ++r) {
                const int rr = row0 + r;
                *(bf16_t*)(smem + KB + rr * 64 + ((d32 * 2) ^ ((rr & 6) << 3))) =
                    (bf16_t)(acc[nt][r] + bias);
            }
        }
        #pragma unroll
        for (int nt = 4; nt < 6; ++nt) {
            const float bias = bqkv[hh * 96 + nt * 16 + l15];
            const int d32 = ((nt & 1) << 4) + l15;
            const int vswz = (wv < 8) ? (((d32 >> 2) & 3) << 4) : 0;
            bf16x4 vvv;
            #pragma unroll
            for (int r = 0; r < 4; ++r)
                vvv[r] = (bf16_t)(acc[nt][r] + bias);
            *(bf16x4*)(smem + VB + d32 * 288 + ((row0 * 2) ^ vswz)) = vvv;
        }
    };

    #pragma unroll
    for (int i3 = 0; i3 < 3; ++i3) {
        const int h0 = i3 * 2, h1 = h0 + 1;

        // ---- QKV both heads of the pair ----
        bf16_t q8a[8], q8b[8];
        qkv_scatter(h0, WB0, q8a);
        qkv_scatter(h1, WB1, q8b);
        __syncthreads();              // BAR1: K/Vt pair visible; WB reads done

        // ---- async-stage next W pair (or Wp halves in last iter) ----
        {
            const char* __restrict__ n0 = (i3 < 2)
                ? ((const char*)Wqkv + (size_t)(h0 + 2) * 36864) : (const char*)Wp;
            const char* __restrict__ n1 = (i3 < 2)
                ? ((const char*)Wqkv + (size_t)(h1 + 2) * 36864) : ((const char*)Wp + 36864);
            #pragma unroll
            for (int i = 0; i < 4; ++i) {
                const int base = wv * 64 + i * 576;
                GLDS16(n0 + (size_t)(base + lane) * 16, smem + WB0 + base * 16);
            }
            #pragma unroll
            for (int i = 0; i < 4; ++i) {
                const int base = wv * 64 + i * 576;
                GLDS16(n1 + (size_t)(base + lane) * 16, smem + WB1 + base * 16);
            }
        }

        // ---- Q transposes: h0 -> chunk0, h1 -> chunk1 ----
        #pragma unroll
        for (int r = 0; r < 4; ++r) {
            const int row = lg * 4 + r;
            const int swz = (row & 6) << 3;
            *(bf16_t*)(pb + row * 64 + ((l15 * 2) ^ swz))             = q8a[r];
            *(bf16_t*)(pb + row * 64 + ((l15 * 2 + 32) ^ swz))        = q8a[4 + r];
            *(bf16_t*)(pb + 1024 + row * 64 + ((l15 * 2) ^ swz))      = q8b[r];
            *(bf16_t*)(pb + 1024 + row * 64 + ((l15 * 2 + 32) ^ swz)) = q8b[4 + r];
        }
        asm volatile("" ::: "memory");
        bf16x8 aq0 = *(const bf16x8*)(pb + l15 * 64 + ((lg * 16) ^ ((l15 & 6) << 3)));
        bf16x8 aq1 = *(const bf16x8*)(pb + 1024 + l15 * 64 + ((lg * 16) ^ ((l15 & 6) << 3)));
        asm volatile("" ::: "memory");

        // ---- fused S-loop: both heads; P stays in REGISTERS (B-frag layout) ----
        float sum0 = 0.f, sum1 = 0.f;
        s16x4 p0[9], p1[9];
        #pragma unroll
        for (int nt = 0; nt < 9; ++nt) {
            const int krow = nt * 16 + l15;
            const int ksw = (lg * 16) ^ ((krow & 6) << 3);
            bf16x8 kf0 = *(const bf16x8*)(smem + K_BASE + krow * 64 + ksw);
            bf16x8 kf1 = *(const bf16x8*)(smem + K_BASE + 9216 + krow * 64 + ksw);
            f32x4 sv0 = MFMA16(kf0, aq0, fzero4());
            f32x4 sv1 = MFMA16(kf1, aq1, fzero4());
            bf16x4 b40 = *(const bf16x4*)(BIASf +
                         (size_t)((((h0 * 9 + wv) * 9 + nt) * 64 + lane) * 4));
            bf16x4 b41 = *(const bf16x4*)(BIASf +
                         (size_t)((((h1 * 9 + wv) * 9 + nt) * 64 + lane) * 4));
            s16x4 w0, w1;
            #pragma unroll
            for (int r = 0; r < 4; ++r) {
                float e0 = exp2f(sv0[r] + (float)b40[r]);
                sum0 += e0;
                w0[r] = f2bf(e0);
                float e1 = exp2f(sv1[r] + (float)b41[r]);
                sum1 += e1;
                w1[r] = f2bf(e1);
            }
            p0[nt] = w0;
            p1[nt] = w1;
        }
        sum0 += __shfl_xor(sum0, 16, 64);
        sum0 += __shfl_xor(sum0, 32, 64);
        sum1 += __shfl_xor(sum1, 16, 64);
        sum1 += __shfl_xor(sum1, 32, 64);
        const float rinv0 = 1.f / sum0;   // lane's q = l15 owns its own rinv
        const float rinv1 = 1.f / sum1;

        // ---- PV both heads: O^T-tiles = mfma_k16(A=Vt, B=P-from-regs) ----
        f32x4 o00 = fzero4(), o01 = fzero4(), o10 = fzero4(), o11 = fzero4();
        const int vswz = ((l15 >> 2) & 3) << 4;
        __builtin_amdgcn_s_setprio(1);
        #pragma unroll
        for (int kt = 0; kt < 9; ++kt) {
            const int byt = (kt < 8) ? ((kt * 32 + lg * 8) ^ vswz) : (256 + lg * 8);
            s16x4 va0 = *(const s16x4*)(smem + VT_BASE + l15 * 288 + byt);
            s16x4 va1 = *(const s16x4*)(smem + VT_BASE + (16 + l15) * 288 + byt);
            s16x4 vb0 = *(const s16x4*)(smem + VT_BASE + 9216 + l15 * 288 + byt);
            s16x4 vb1 = *(const s16x4*)(smem + VT_BASE + 9216 + (16 + l15) * 288 + byt);
            o00 = MFMA_K16(va0, p0[kt], o00);
            o01 = MFMA_K16(va1, p0[kt], o01);
            o10 = MFMA_K16(vb0, p1[kt], o10);
            o11 = MFMA_K16(vb1, p1[kt], o11);
        }
        __builtin_amdgcn_s_setprio(0);

        // ---- normalize in-lane; O already in proj A-frag layout ----
        {
            s16x4 a0, a1, b0, b1;
            #pragma unroll
            for (int r = 0; r < 4; ++r) {
                a0[r] = f2bf(o00[r] * rinv0);
                a1[r] = f2bf(o01[r] * rinv0);
                b0[r] = f2bf(o10[r] * rinv1);
                b1[r] = f2bf(o11[r] * rinv1);
            }
            po[h0 * 2]     = a0;
            po[h0 * 2 + 1] = a1;
            po[h1 * 2]     = b0;
            po[h1 * 2 + 1] = b1;
        }
        __syncthreads();              // BAR2: next W pair staged; K/Vt free
    }

    // ---- output projection (barrier-free): WB0/WB1 = Wp halves, K=16 frags ----
    float* __restrict__ og = out + (size_t)win * 25920;
    #pragma unroll
    for (int half = 0; half < 2; ++half) {
        const int WH = half ? WB1 : WB0;
        f32x4 accp[6];
        #pragma unroll
        for (int nt = 0; nt < 6; ++nt) accp[nt] = fzero4();
        __builtin_amdgcn_s_setprio(1);
        #pragma unroll
        for (int kt = 0; kt < 12; ++kt) {
            #pragma unroll
            for (int nt = 0; nt < 6; ++nt) {
                s16x4 bw = *(const s16x4*)(smem + WH + ((kt * 6 + nt) * 64 + lane) * 8);
                accp[nt] = MFMA_K16(po[kt], bw, accp[nt]);
            }
        }
        __builtin_amdgcn_s_setprio(0);
        #pragma unroll
        for (int nt = 0; nt < 6; ++nt) {
            const int col = half * 96 + nt * 16 + l15;
            if (col < 180) {
                const float bias = bp[col];
                #pragma unroll
                for (int r = 0; r < 4; ++r) {
                    const int row = wv * 16 + lg * 4 + r;
                    og[row * 180 + col] = accp[nt][r] + bias;
                }
            }
        }
    }
}

extern "C" void kernel_launch(void* const* d_in, const int* in_sizes, int n_in,
                              void* d_out, int out_size, void* d_ws, size_t ws_size,
                              hipStream_t stream) {
    const float* gs = (const float*)d_in[0];
    const float* wq = (const float*)d_in[1];
    const float* bq = (const float*)d_in[2];
    const float* wk = (const float*)d_in[3];
    const float* bk = (const float*)d_in[4];
    const float* wv = (const float*)d_in[5];
    const float* bv = (const float*)d_in[6];
    const float* wp = (const float*)d_in[7];
    const float* bp = (const float*)d_in[8];
    const float* bt = (const float*)d_in[9];

    char* ws = (char*)d_ws;
    bf16_t* Wqkv  = (bf16_t*)(ws);
    bf16_t* Wp    = (bf16_t*)(ws + 221184);
    bf16_t* BIASf = (bf16_t*)(ws + 294912);
    float*  bqkv  = (float*)(ws + 543744);

    pack_kernel<<<256, 256, 0, stream>>>(wq, bq, wk, bk, wv, bv, wp, bt,
                                         Wqkv, Wp, BIASf, bqkv);
    attn_kernel<<<2048, 576, 0, stream>>>(gs, Wqkv, Wp, BIASf, bqkv, bp, (float*)d_out);
}

// Round 15
// 352.444 us; speedup vs baseline: 1.2161x; 1.2161x over previous
//
#include <hip/hip_runtime.h>

// GSSelfAttn: B=2048 windows, N=144 tokens, D=180, H=6 heads, hd=30.
// R15: R11 base + uniform PV (Vt stride 320 w/ zeroed pad toks 144-159,
// P-tail chunk 64B rows w/ zeroed pad -> no divergent tail, no zero-regs),
// raw v_exp/v_rcp on softmax chain, pack grid 512. Register-neutral.
// LDS 158720: WB0/WB1 2x36864 | strips 9x5120 | K[2] 18432 | Vt[2] 20480.

typedef __bf16 bf16_t;
typedef __bf16 bf16x8 __attribute__((ext_vector_type(8)));
typedef __bf16 bf16x4 __attribute__((ext_vector_type(4)));
typedef float f32x4 __attribute__((ext_vector_type(4)));

#define MFMA16(a, b, c) __builtin_amdgcn_mfma_f32_16x16x32_bf16((a), (b), (c), 0, 0, 0)
#define GLDS16(g, l) __builtin_amdgcn_global_load_lds(                         \
    (const __attribute__((address_space(1))) void*)(g),                        \
    (__attribute__((address_space(3))) void*)(l), 16, 0, 0)

static __device__ __forceinline__ f32x4 fzero4() {
    f32x4 z; z[0] = 0.f; z[1] = 0.f; z[2] = 0.f; z[3] = 0.f; return z;
}

// ---------------- pack kernel (identical to R11) ----------------
// ws layout (bytes):
//   Wqkv  @ 0      : [h][kt6][nt6][lane64][j8] bf16      = 221184 B  (Q cols *30^-.5*log2e)
//   Wp    @ 221184 : [half2][kt6][ntl6][lane64][j8] bf16 =  73728 B  (half-major)
//   BIASf @ 294912 : [h][wv9][nt9][lane64][r4] bf16      = 248832 B  (S^T frag layout, *log2e)
//   bqkv  @ 543744 : [h][c96] fp32                       =   2304 B  (Q part *scale*log2e)
__global__ void pack_kernel(const float* __restrict__ wq, const float* __restrict__ bq,
                            const float* __restrict__ wk, const float* __restrict__ bk,
                            const float* __restrict__ wv, const float* __restrict__ bv,
                            const float* __restrict__ wp, const float* __restrict__ bt,
                            bf16_t* __restrict__ Wqkv, bf16_t* __restrict__ Wp,
                            bf16_t* __restrict__ BIASf, float* __restrict__ bqkv)
{
    const int t = blockIdx.x * blockDim.x + threadIdx.x;
    const int stride = gridDim.x * blockDim.x;
    const float L2E = 1.4426950408889634f;
    const float qscale = 0.18257418583505536f * L2E;

    for (int i = t; i < 6 * 6 * 6 * 512; i += stride) {
        int j = i & 7, lane = (i >> 3) & 63;
        int f = i >> 9;               // [h][kt][nt]
        int nt = f % 6, kt = (f / 6) % 6, h = f / 36;
        int kin = kt * 32 + (lane >> 4) * 8 + j;
        int c = nt * 16 + (lane & 15);       // 0..95
        int sec = c >> 5, d = c & 31;
        float v = 0.f;
        if (kin < 180 && d < 30) {
            int col = h * 30 + d;
            if (sec == 0)      v = wq[kin * 180 + col] * qscale;
            else if (sec == 1) v = wk[kin * 180 + col];
            else               v = wv[kin * 180 + col];
        }
        Wqkv[i] = (bf16_t)v;
    }
    for (int i = t; i < 2 * 6 * 6 * 512; i += stride) {
        int j = i & 7, lane = (i >> 3) & 63;
        int f = i >> 9;               // [half][kt][ntl]
        int ntl = f % 6, kt = (f / 6) % 6, half = f / 36;
        int nt = half * 6 + ntl;
        int kin = kt * 32 + (lane >> 4) * 8 + j;
        int hh = kin >> 5, d = kin & 31;
        int cout = nt * 16 + (lane & 15);
        float v = 0.f;
        if (d < 30 && cout < 180) v = wp[(hh * 30 + d) * 180 + cout];
        Wp[i] = (bf16_t)v;
    }
    for (int i = t; i < 6 * 9 * 9 * 64; i += stride) {
        int lane = i & 63;
        int f = i >> 6;               // [h][wv][nt]
        int nt = f % 9, wvq = (f / 9) % 9, h = f / 81;
        int q = wvq * 16 + (lane & 15);
        int qi = q / 12, qj = q % 12;
        #pragma unroll
        for (int r = 0; r < 4; ++r) {
            int k = nt * 16 + (lane >> 4) * 4 + r;
            int ki = k / 12, kj = k % 12;
            int rel = (qi - ki + 11) * 23 + (qj - kj + 11);
            BIASf[i * 4 + r] = (bf16_t)(bt[rel * 6 + h] * L2E);
        }
    }
    for (int i = t; i < 576; i += stride) {
        int c = i % 96, h = i / 96;
        int sec = c >> 5, d = c & 31;
        float v = 0.f;
        if (d < 30) {
            if (sec == 0)      v = bq[h * 30 + d] * qscale;
            else if (sec == 1) v = bk[h * 30 + d];
            else               v = bv[h * 30 + d];
        }
        bqkv[i] = v;
    }
}

// ---------------- fused attention kernel ----------------
// block = 576 threads = 9 waves; wave wv owns M-strip rows [16wv, 16wv+16)
// LDS map (158720 B):
//   WB0   @ 0      : 36864 (even-head W; Wp half0 in last iter)
//   WB1   @ 36864  : 36864 (odd-head W; Wp half1 in last iter)
//   strips@ 73728  : 9 x 5120 (P chunks0-3 [16q][32tok] swizzled + tail chunk
//                    [16q][64B] (toks 128-143 + zeroed pad); chunk0/1 double as
//                    Q transpose scratch between uses)
//   K[2]  @ 119808 : per-head-parity [144][32] bf16, swizzle ^((row&6)<<3)
//   Vt[2] @ 138240 : per-head-parity [32][160] bf16 stride 320, 64B-blks 0..3
//                    swizzled, toks 144-159 zeroed once
__global__ __launch_bounds__(576, 2)
void attn_kernel(const float* __restrict__ gs,
                 const bf16_t* __restrict__ Wqkv, const bf16_t* __restrict__ Wp,
                 const bf16_t* __restrict__ BIASf, const float* __restrict__ bqkv,
                 const float* __restrict__ bp, float* __restrict__ out)
{
    __shared__ __align__(16) unsigned char smem[158720];

    const int tid = threadIdx.x;
    const int lane = tid & 63;
    const int wv = tid >> 6;          // wave id = M-strip 0..8
    const int l15 = lane & 15;
    const int lg = lane >> 4;         // 0..3
    const int win = blockIdx.x;
    const float* __restrict__ gsw = gs + (size_t)win * 25920;

    constexpr int WB0     = 0;
    constexpr int WB1     = 36864;
    constexpr int ST_BASE = 73728;
    constexpr int K_BASE  = 119808;   // + parity*9216
    constexpr int VT_BASE = 138240;   // + parity*10240

    char* const pb = (char*)smem + ST_BASE + wv * 5120;   // wave-private strip
    const int pswz = (l15 & 6) << 3;

    // ---- prologue: async-stage W(0)->WB0, W(1)->WB1; load gs; zero pads ----
    #pragma unroll
    for (int i = 0; i < 4; ++i) {
        const int base = wv * 64 + i * 576;
        GLDS16((const char*)Wqkv + (size_t)(base + lane) * 16, smem + WB0 + base * 16);
    }
    #pragma unroll
    for (int i = 0; i < 4; ++i) {
        const int base = wv * 64 + i * 576;
        GLDS16((const char*)Wqkv + 36864 + (size_t)(base + lane) * 16, smem + WB1 + base * 16);
    }

    // zero P-tail pad (logical toks 144-159 of tail chunk; pswz-consistent)
    *(unsigned long long*)(pb + 4096 + l15 * 64 + ((32 + lg * 8) ^ pswz)) = 0ull;
    // zero Vt pad toks 144-159 (bytes 288-319) in both parity buffers
    if (tid < 256) {
        const int buf = tid >> 7, d = (tid >> 2) & 31, c = tid & 3;
        *(unsigned long long*)(smem + VT_BASE + buf * 10240 + d * 320 + 288 + c * 8) = 0ull;
    }

    bf16x8 xa[6];
    {
        const int row = wv * 16 + l15;
        const float4* __restrict__ g4 = (const float4*)(gsw + row * 180);
        #pragma unroll
        for (int kt = 0; kt < 6; ++kt) {
            const int c0 = kt * 32 + lg * 8;
            float4 lo = {0.f, 0.f, 0.f, 0.f}, hi = {0.f, 0.f, 0.f, 0.f};
            if (c0 + 4 <= 180) lo = g4[c0 >> 2];
            if (c0 + 8 <= 180) hi = g4[(c0 >> 2) + 1];
            bf16x8 v;
            v[0] = (bf16_t)lo.x; v[1] = (bf16_t)lo.y; v[2] = (bf16_t)lo.z; v[3] = (bf16_t)lo.w;
            v[4] = (bf16_t)hi.x; v[5] = (bf16_t)hi.y; v[6] = (bf16_t)hi.z; v[7] = (bf16_t)hi.w;
            xa[kt] = v;
        }
    }
    __syncthreads();                  // drains glds: W(0),W(1) staged; pads zeroed

    bf16x8 ao[6];                     // per-head O A-fragments (persistent)
    const int row0 = wv * 16 + lg * 4;

    // QKV GEMM for head hh reading WB at wbofs; Q->q8o, K/Vt->parity(hh) LDS
    auto qkv_scatter = [&](const int hh, const int wbofs, bf16_t* q8o) {
        const int KB = K_BASE + (hh & 1) * 9216;
        const int VB = VT_BASE + (hh & 1) * 10240;
        f32x4 acc[6];
        #pragma unroll
        for (int nt = 0; nt < 6; ++nt) acc[nt] = fzero4();
        __builtin_amdgcn_s_setprio(1);
        #pragma unroll
        for (int kt = 0; kt < 6; ++kt) {
            #pragma unroll
            for (int nt = 0; nt < 6; ++nt) {
                bf16x8 bw = *(const bf16x8*)(smem + wbofs + ((kt * 6 + nt) * 64 + lane) * 16);
                acc[nt] = MFMA16(xa[kt], bw, acc[nt]);
            }
        }
        __builtin_amdgcn_s_setprio(0);
        #pragma unroll
        for (int nt = 0; nt < 2; ++nt) {
            const float bias = bqkv[hh * 96 + nt * 16 + l15];
            #pragma unroll
            for (int r = 0; r < 4; ++r)
                q8o[nt * 4 + r] = (bf16_t)(acc[nt][r] + bias);
        }
        #pragma unroll
        for (int nt = 2; nt < 4; ++nt) {
            const float bias = bqkv[hh * 96 + nt * 16 + l15];
            const int d32 = ((nt & 1) << 4) + l15;
            #pragma unroll
            for (int r = 0; r < 4; ++r) {
                const int rr = row0 + r;
                *(bf16_t*)(smem + KB + rr * 64 + ((d32 * 2) ^ ((rr & 6) << 3))) =
                    (bf16_t)(acc[nt][r] + bias);
            }
        }
        #pragma unroll
        for (int nt = 4; nt < 6; ++nt) {
            const float bias = bqkv[hh * 96 + nt * 16 + l15];
            const int d32 = ((nt & 1) << 4) + l15;
            const int vswz = (wv < 8) ? (((d32 >> 2) & 3) << 4) : 0;
            bf16x4 vvv;
            #pragma unroll
            for (int r = 0; r < 4; ++r)
                vvv[r] = (bf16_t)(acc[nt][r] + bias);
            *(bf16x4*)(smem + VB + d32 * 320 + ((row0 * 2) ^ vswz)) = vvv;
        }
    };

    #pragma unroll
    for (int i3 = 0; i3 < 3; ++i3) {
        const int h0 = i3 * 2, h1 = h0 + 1;

        // ---- QKV both heads of the pair ----
        bf16_t q8a[8], q8b[8];
        qkv_scatter(h0, WB0, q8a);
        qkv_scatter(h1, WB1, q8b);
        __syncthreads();              // BAR1: K/Vt pair visible; WB reads done

        // ---- async-stage next W pair (or Wp halves in last iter) ----
        {
            const char* __restrict__ n0 = (i3 < 2)
                ? ((const char*)Wqkv + (size_t)(h0 + 2) * 36864) : (const char*)Wp;
            const char* __restrict__ n1 = (i3 < 2)
                ? ((const char*)Wqkv + (size_t)(h1 + 2) * 36864) : ((const char*)Wp + 36864);
            #pragma unroll
            for (int i = 0; i < 4; ++i) {
                const int base = wv * 64 + i * 576;
                GLDS16(n0 + (size_t)(base + lane) * 16, smem + WB0 + base * 16);
            }
            #pragma unroll
            for (int i = 0; i < 4; ++i) {
                const int base = wv * 64 + i * 576;
                GLDS16(n1 + (size_t)(base + lane) * 16, smem + WB1 + base * 16);
            }
        }

        // ---- Q transposes: h0 -> chunk0, h1 -> chunk1 ----
        #pragma unroll
        for (int r = 0; r < 4; ++r) {
            const int row = lg * 4 + r;
            const int swz = (row & 6) << 3;
            *(bf16_t*)(pb + row * 64 + ((l15 * 2) ^ swz))             = q8a[r];
            *(bf16_t*)(pb + row * 64 + ((l15 * 2 + 32) ^ swz))        = q8a[4 + r];
            *(bf16_t*)(pb + 1024 + row * 64 + ((l15 * 2) ^ swz))      = q8b[r];
            *(bf16_t*)(pb + 1024 + row * 64 + ((l15 * 2 + 32) ^ swz)) = q8b[4 + r];
        }
        asm volatile("" ::: "memory");
        bf16x8 aq0 = *(const bf16x8*)(pb + l15 * 64 + ((lg * 16) ^ ((l15 & 6) << 3)));
        bf16x8 aq1 = *(const bf16x8*)(pb + 1024 + l15 * 64 + ((lg * 16) ^ ((l15 & 6) << 3)));
        asm volatile("" ::: "memory");

        // ---- fused S-loop: both heads per nt (2 indep streams) ----
        float sum0 = 0.f, sum1 = 0.f;
        f32x4 s1[9];
        #pragma unroll
        for (int nt = 0; nt < 9; ++nt) {
            const int krow = nt * 16 + l15;
            const int ksw = (lg * 16) ^ ((krow & 6) << 3);
            bf16x8 kf0 = *(const bf16x8*)(smem + K_BASE + krow * 64 + ksw);
            bf16x8 kf1 = *(const bf16x8*)(smem + K_BASE + 9216 + krow * 64 + ksw);
            f32x4 sv0 = MFMA16(kf0, aq0, fzero4());
            f32x4 sv1 = MFMA16(kf1, aq1, fzero4());
            bf16x4 b40 = *(const bf16x4*)(BIASf +
                         (size_t)((((h0 * 9 + wv) * 9 + nt) * 64 + lane) * 4));
            bf16x4 b41 = *(const bf16x4*)(BIASf +
                         (size_t)((((h1 * 9 + wv) * 9 + nt) * 64 + lane) * 4));
            bf16x4 pw;
            #pragma unroll
            for (int r = 0; r < 4; ++r) {
                float p = __builtin_amdgcn_exp2f(sv0[r] + (float)b40[r]);
                sum0 += p;
                pw[r] = (bf16_t)p;
                float q = __builtin_amdgcn_exp2f(sv1[r] + (float)b41[r]);
                sum1 += q;
                s1[nt][r] = q;
            }
            if (nt < 8)
                *(bf16x4*)(pb + (nt >> 1) * 1024 + l15 * 64 +
                           ((((nt & 1) << 5) + lg * 8) ^ pswz)) = pw;
            else
                *(bf16x4*)(pb + 4096 + l15 * 64 + ((lg * 8) ^ pswz)) = pw;
        }
        sum0 += __shfl_xor(sum0, 16, 64);
        sum0 += __shfl_xor(sum0, 32, 64);
        sum1 += __shfl_xor(sum1, 16, 64);
        sum1 += __shfl_xor(sum1, 32, 64);
        const float rinv0 = __builtin_amdgcn_rcpf(sum0);
        const float rinv1 = __builtin_amdgcn_rcpf(sum1);
        asm volatile("" ::: "memory");

        // ---- PV(h0): uniform 5 kt, no tail divergence ----
        f32x4 o00 = fzero4(), o01 = fzero4();
        __builtin_amdgcn_s_setprio(1);
        #pragma unroll
        for (int kt = 0; kt < 5; ++kt) {
            const int vs0 = (kt < 4) ? (((l15 >> 2) & 3) << 4) : 0;
            bf16x8 ap  = *(const bf16x8*)(pb + kt * 1024 + l15 * 64 + ((lg * 16) ^ pswz));
            bf16x8 bv0 = *(const bf16x8*)(smem + VT_BASE + l15 * 320 + kt * 64 + ((lg * 16) ^ vs0));
            bf16x8 bv1 = *(const bf16x8*)(smem + VT_BASE + (16 + l15) * 320 + kt * 64 + ((lg * 16) ^ vs0));
            o00 = MFMA16(ap, bv0, o00);
            o01 = MFMA16(ap, bv1, o01);
        }
        __builtin_amdgcn_s_setprio(0);
        asm volatile("" ::: "memory");

        // ---- P(h1) -> strip (after PV(h0) reads; in-wave DS order) ----
        #pragma unroll
        for (int nt = 0; nt < 9; ++nt) {
            bf16x4 pw;
            #pragma unroll
            for (int r = 0; r < 4; ++r) pw[r] = (bf16_t)s1[nt][r];
            if (nt < 8)
                *(bf16x4*)(pb + (nt >> 1) * 1024 + l15 * 64 +
                           ((((nt & 1) << 5) + lg * 8) ^ pswz)) = pw;
            else
                *(bf16x4*)(pb + 4096 + l15 * 64 + ((lg * 8) ^ pswz)) = pw;
        }
        asm volatile("" ::: "memory");

        // ---- PV(h1): uniform 5 kt ----
        f32x4 o10 = fzero4(), o11 = fzero4();
        __builtin_amdgcn_s_setprio(1);
        #pragma unroll
        for (int kt = 0; kt < 5; ++kt) {
            const int vs0 = (kt < 4) ? (((l15 >> 2) & 3) << 4) : 0;
            bf16x8 ap  = *(const bf16x8*)(pb + kt * 1024 + l15 * 64 + ((lg * 16) ^ pswz));
            bf16x8 bv0 = *(const bf16x8*)(smem + VT_BASE + 10240 + l15 * 320 + kt * 64 + ((lg * 16) ^ vs0));
            bf16x8 bv1 = *(const bf16x8*)(smem + VT_BASE + 10240 + (16 + l15) * 320 + kt * 64 + ((lg * 16) ^ vs0));
            o10 = MFMA16(ap, bv0, o10);
            o11 = MFMA16(ap, bv1, o11);
        }
        __builtin_amdgcn_s_setprio(0);
        asm volatile("" ::: "memory");

        // ---- normalize + O transposes: h0 -> chunk0, h1 -> chunk1 ----
        #pragma unroll
        for (int r = 0; r < 4; ++r) {
            const float rq0 = __shfl(rinv0, lg * 4 + r, 16);
            const float rq1 = __shfl(rinv1, lg * 4 + r, 16);
            const int row = lg * 4 + r;
            const int swz = (row & 6) << 3;
            *(bf16_t*)(pb + row * 64 + ((l15 * 2) ^ swz))             = (bf16_t)(o00[r] * rq0);
            *(bf16_t*)(pb + row * 64 + ((l15 * 2 + 32) ^ swz))        = (bf16_t)(o01[r] * rq0);
            *(bf16_t*)(pb + 1024 + row * 64 + ((l15 * 2) ^ swz))      = (bf16_t)(o10[r] * rq1);
            *(bf16_t*)(pb + 1024 + row * 64 + ((l15 * 2 + 32) ^ swz)) = (bf16_t)(o11[r] * rq1);
        }
        asm volatile("" ::: "memory");
        ao[h0] = *(const bf16x8*)(pb + l15 * 64 + ((lg * 16) ^ ((l15 & 6) << 3)));
        ao[h1] = *(const bf16x8*)(pb + 1024 + l15 * 64 + ((lg * 16) ^ ((l15 & 6) << 3)));

        __syncthreads();              // BAR2: next W pair staged; K/Vt free
    }

    // ---- output projection (barrier-free): WB0 = Wp half0, WB1 = Wp half1 ----
    float* __restrict__ og = out + (size_t)win * 25920;
    #pragma unroll
    for (int half = 0; half < 2; ++half) {
        const int WH = half ? WB1 : WB0;
        f32x4 accp[6];
        #pragma unroll
        for (int nt = 0; nt < 6; ++nt) accp[nt] = fzero4();
        __builtin_amdgcn_s_setprio(1);
        #pragma unroll
        for (int kt = 0; kt < 6; ++kt) {
            #pragma unroll
            for (int nt = 0; nt < 6; ++nt) {
                bf16x8 bw = *(const bf16x8*)(smem + WH + ((kt * 6 + nt) * 64 + lane) * 16);
                accp[nt] = MFMA16(ao[kt], bw, accp[nt]);
            }
        }
        __builtin_amdgcn_s_setprio(0);
        #pragma unroll
        for (int nt = 0; nt < 6; ++nt) {
            const int col = half * 96 + nt * 16 + l15;
            if (col < 180) {
                const float bias = bp[col];
                #pragma unroll
                for (int r = 0; r < 4; ++r) {
                    const int row = wv * 16 + lg * 4 + r;
                    og[row * 180 + col] = accp[nt][r] + bias;
                }
            }
        }
    }
}

extern "C" void kernel_launch(void* const* d_in, const int* in_sizes, int n_in,
                              void* d_out, int out_size, void* d_ws, size_t ws_size,
                              hipStream_t stream) {
    const float* gs = (const float*)d_in[0];
    const float* wq = (const float*)d_in[1];
    const float* bq = (const float*)d_in[2];
    const float* wk = (const float*)d_in[3];
    const float* bk = (const float*)d_in[4];
    const float* wv = (const float*)d_in[5];
    const float* bv = (const float*)d_in[6];
    const float* wp = (const float*)d_in[7];
    const float* bp = (const float*)d_in[8];
    const float* bt = (const float*)d_in[9];

    char* ws = (char*)d_ws;
    bf16_t* Wqkv  = (bf16_t*)(ws);
    bf16_t* Wp    = (bf16_t*)(ws + 221184);
    bf16_t* BIASf = (bf16_t*)(ws + 294912);
    float*  bqkv  = (float*)(ws + 543744);

    pack_kernel<<<512, 256, 0, stream>>>(wq, bq, wk, bk, wv, bv, wp, bt,
                                         Wqkv, Wp, BIASf, bqkv);
    attn_kernel<<<2048, 576, 0, stream>>>(gs, Wqkv, Wp, BIASf, bqkv, bp, (float*)d_out);
}

// Round 16
// 294.069 us; speedup vs baseline: 1.4575x; 1.1985x over previous
//
#include <hip/hip_runtime.h>

// GSSelfAttn: B=2048 windows, N=144 tokens, D=180, H=6 heads, hd=30.
// R16: R11 (best, 325us) + minimal micro-edits only:
//  - __builtin_amdgcn_exp2f on the softmax chain (no OCML wrapper)
//  - __builtin_amdgcn_rcpf for 1/sum
//  - pack grid 512
// Everything else identical to R11 (Vt stride 288; R15's stride-320 regression
// reverted). Head-paired iters, glds W prefetch, barrier-free epilogue.
// LDS 152064: WB0/WB1 2x36864 | strips 41472 | K[2] 18432 | Vt[2] 18432.

typedef __bf16 bf16_t;
typedef __bf16 bf16x8 __attribute__((ext_vector_type(8)));
typedef __bf16 bf16x4 __attribute__((ext_vector_type(4)));
typedef float f32x4 __attribute__((ext_vector_type(4)));

#define MFMA16(a, b, c) __builtin_amdgcn_mfma_f32_16x16x32_bf16((a), (b), (c), 0, 0, 0)
#define GLDS16(g, l) __builtin_amdgcn_global_load_lds(                         \
    (const __attribute__((address_space(1))) void*)(g),                        \
    (__attribute__((address_space(3))) void*)(l), 16, 0, 0)

static __device__ __forceinline__ f32x4 fzero4() {
    f32x4 z; z[0] = 0.f; z[1] = 0.f; z[2] = 0.f; z[3] = 0.f; return z;
}
static __device__ __forceinline__ bf16x8 bzero8() {
    bf16x8 z;
    #pragma unroll
    for (int i = 0; i < 8; ++i) z[i] = (bf16_t)0.f;
    return z;
}

// ---------------- pack kernel (identical to R11) ----------------
// ws layout (bytes):
//   Wqkv  @ 0      : [h][kt6][nt6][lane64][j8] bf16      = 221184 B  (Q cols *30^-.5*log2e)
//   Wp    @ 221184 : [half2][kt6][ntl6][lane64][j8] bf16 =  73728 B  (half-major)
//   BIASf @ 294912 : [h][wv9][nt9][lane64][r4] bf16      = 248832 B  (S^T frag layout, *log2e)
//   bqkv  @ 543744 : [h][c96] fp32                       =   2304 B  (Q part *scale*log2e)
__global__ void pack_kernel(const float* __restrict__ wq, const float* __restrict__ bq,
                            const float* __restrict__ wk, const float* __restrict__ bk,
                            const float* __restrict__ wv, const float* __restrict__ bv,
                            const float* __restrict__ wp, const float* __restrict__ bt,
                            bf16_t* __restrict__ Wqkv, bf16_t* __restrict__ Wp,
                            bf16_t* __restrict__ BIASf, float* __restrict__ bqkv)
{
    const int t = blockIdx.x * blockDim.x + threadIdx.x;
    const int stride = gridDim.x * blockDim.x;
    const float L2E = 1.4426950408889634f;
    const float qscale = 0.18257418583505536f * L2E;

    for (int i = t; i < 6 * 6 * 6 * 512; i += stride) {
        int j = i & 7, lane = (i >> 3) & 63;
        int f = i >> 9;               // [h][kt][nt]
        int nt = f % 6, kt = (f / 6) % 6, h = f / 36;
        int kin = kt * 32 + (lane >> 4) * 8 + j;
        int c = nt * 16 + (lane & 15);       // 0..95
        int sec = c >> 5, d = c & 31;
        float v = 0.f;
        if (kin < 180 && d < 30) {
            int col = h * 30 + d;
            if (sec == 0)      v = wq[kin * 180 + col] * qscale;
            else if (sec == 1) v = wk[kin * 180 + col];
            else               v = wv[kin * 180 + col];
        }
        Wqkv[i] = (bf16_t)v;
    }
    for (int i = t; i < 2 * 6 * 6 * 512; i += stride) {
        int j = i & 7, lane = (i >> 3) & 63;
        int f = i >> 9;               // [half][kt][ntl]
        int ntl = f % 6, kt = (f / 6) % 6, half = f / 36;
        int nt = half * 6 + ntl;
        int kin = kt * 32 + (lane >> 4) * 8 + j;
        int hh = kin >> 5, d = kin & 31;
        int cout = nt * 16 + (lane & 15);
        float v = 0.f;
        if (d < 30 && cout < 180) v = wp[(hh * 30 + d) * 180 + cout];
        Wp[i] = (bf16_t)v;
    }
    for (int i = t; i < 6 * 9 * 9 * 64; i += stride) {
        int lane = i & 63;
        int f = i >> 6;               // [h][wv][nt]
        int nt = f % 9, wvq = (f / 9) % 9, h = f / 81;
        int q = wvq * 16 + (lane & 15);
        int qi = q / 12, qj = q % 12;
        #pragma unroll
        for (int r = 0; r < 4; ++r) {
            int k = nt * 16 + (lane >> 4) * 4 + r;
            int ki = k / 12, kj = k % 12;
            int rel = (qi - ki + 11) * 23 + (qj - kj + 11);
            BIASf[i * 4 + r] = (bf16_t)(bt[rel * 6 + h] * L2E);
        }
    }
    for (int i = t; i < 576; i += stride) {
        int c = i % 96, h = i / 96;
        int sec = c >> 5, d = c & 31;
        float v = 0.f;
        if (d < 30) {
            if (sec == 0)      v = bq[h * 30 + d] * qscale;
            else if (sec == 1) v = bk[h * 30 + d];
            else               v = bv[h * 30 + d];
        }
        bqkv[i] = v;
    }
}

// ---------------- fused attention kernel ----------------
// block = 576 threads = 9 waves; wave wv owns M-strip rows [16wv, 16wv+16)
// LDS map (152064 B):
//   WB0   @ 0      : 36864 (even-head W; Wp half0 in last iter)
//   WB1   @ 36864  : 36864 (odd-head W; Wp half1 in last iter)
//   strips@ 73728  : 9 x 4608 (P chunks0-3 [16q][32tok] swizzled + 512B tail;
//                    chunk0/1 double as Q/O transpose scratch between uses)
//   K[2]  @ 115200 : per-head-parity [144][32] bf16, swizzle ^((row&6)<<3)
//   Vt[2] @ 133632 : per-head-parity [32][144] bf16 stride 288, d-blk swizzled
__global__ __launch_bounds__(576, 2)
void attn_kernel(const float* __restrict__ gs,
                 const bf16_t* __restrict__ Wqkv, const bf16_t* __restrict__ Wp,
                 const bf16_t* __restrict__ BIASf, const float* __restrict__ bqkv,
                 const float* __restrict__ bp, float* __restrict__ out)
{
    __shared__ __align__(16) unsigned char smem[152064];

    const int tid = threadIdx.x;
    const int lane = tid & 63;
    const int wv = tid >> 6;          // wave id = M-strip 0..8
    const int l15 = lane & 15;
    const int lg = lane >> 4;         // 0..3
    const int win = blockIdx.x;
    const float* __restrict__ gsw = gs + (size_t)win * 25920;

    constexpr int WB0     = 0;
    constexpr int WB1     = 36864;
    constexpr int ST_BASE = 73728;
    constexpr int K_BASE  = 115200;   // + parity*9216
    constexpr int VT_BASE = 133632;   // + parity*9216

    // ---- prologue: async-stage W(0)->WB0, W(1)->WB1; load gs ----
    #pragma unroll
    for (int i = 0; i < 4; ++i) {
        const int base = wv * 64 + i * 576;
        GLDS16((const char*)Wqkv + (size_t)(base + lane) * 16, smem + WB0 + base * 16);
    }
    #pragma unroll
    for (int i = 0; i < 4; ++i) {
        const int base = wv * 64 + i * 576;
        GLDS16((const char*)Wqkv + 36864 + (size_t)(base + lane) * 16, smem + WB1 + base * 16);
    }

    bf16x8 xa[6];
    {
        const int row = wv * 16 + l15;
        const float4* __restrict__ g4 = (const float4*)(gsw + row * 180);
        #pragma unroll
        for (int kt = 0; kt < 6; ++kt) {
            const int c0 = kt * 32 + lg * 8;
            float4 lo = {0.f, 0.f, 0.f, 0.f}, hi = {0.f, 0.f, 0.f, 0.f};
            if (c0 + 4 <= 180) lo = g4[c0 >> 2];
            if (c0 + 8 <= 180) hi = g4[(c0 >> 2) + 1];
            bf16x8 v;
            v[0] = (bf16_t)lo.x; v[1] = (bf16_t)lo.y; v[2] = (bf16_t)lo.z; v[3] = (bf16_t)lo.w;
            v[4] = (bf16_t)hi.x; v[5] = (bf16_t)hi.y; v[6] = (bf16_t)hi.z; v[7] = (bf16_t)hi.w;
            xa[kt] = v;
        }
    }
    __syncthreads();                  // drains glds: W(0),W(1) staged

    bf16x8 ao[6];                     // per-head O A-fragments (persistent)
    char* const pb = (char*)smem + ST_BASE + wv * 4608;   // wave-private strip
    const int pswz = (l15 & 6) << 3;
    const int row0 = wv * 16 + lg * 4;

    // QKV GEMM for head hh reading WB at wbofs; Q->q8o, K/Vt->parity(hh) LDS
    auto qkv_scatter = [&](const int hh, const int wbofs, bf16_t* q8o) {
        const int KB = K_BASE + (hh & 1) * 9216;
        const int VB = VT_BASE + (hh & 1) * 9216;
        f32x4 acc[6];
        #pragma unroll
        for (int nt = 0; nt < 6; ++nt) acc[nt] = fzero4();
        __builtin_amdgcn_s_setprio(1);
        #pragma unroll
        for (int kt = 0; kt < 6; ++kt) {
            #pragma unroll
            for (int nt = 0; nt < 6; ++nt) {
                bf16x8 bw = *(const bf16x8*)(smem + wbofs + ((kt * 6 + nt) * 64 + lane) * 16);
                acc[nt] = MFMA16(xa[kt], bw, acc[nt]);
            }
        }
        __builtin_amdgcn_s_setprio(0);
        #pragma unroll
        for (int nt = 0; nt < 2; ++nt) {
            const float bias = bqkv[hh * 96 + nt * 16 + l15];
            #pragma unroll
            for (int r = 0; r < 4; ++r)
                q8o[nt * 4 + r] = (bf16_t)(acc[nt][r] + bias);
        }
        #pragma unroll
        for (int nt = 2; nt < 4; ++nt) {
            const float bias = bqkv[hh * 96 + nt * 16 + l15];
            const int d32 = ((nt & 1) << 4) + l15;
            #pragma unroll
            for (int r = 0; r < 4; ++r) {
                const int rr = row0 + r;
                *(bf16_t*)(smem + KB + rr * 64 + ((d32 * 2) ^ ((rr & 6) << 3))) =
                    (bf16_t)(acc[nt][r] + bias);
            }
        }
        #pragma unroll
        for (int nt = 4; nt < 6; ++nt) {
            const float bias = bqkv[hh * 96 + nt * 16 + l15];
            const int d32 = ((nt & 1) << 4) + l15;
            const int vswz = (wv < 8) ? (((d32 >> 2) & 3) << 4) : 0;
            bf16x4 vvv;
            #pragma unroll
            for (int r = 0; r < 4; ++r)
                vvv[r] = (bf16_t)(acc[nt][r] + bias);
            *(bf16x4*)(smem + VB + d32 * 288 + ((row0 * 2) ^ vswz)) = vvv;
        }
    };

    #pragma unroll
    for (int i3 = 0; i3 < 3; ++i3) {
        const int h0 = i3 * 2, h1 = h0 + 1;

        // ---- QKV both heads of the pair ----
        bf16_t q8a[8], q8b[8];
        qkv_scatter(h0, WB0, q8a);
        qkv_scatter(h1, WB1, q8b);
        __syncthreads();              // BAR1: K/Vt pair visible; WB reads done

        // ---- async-stage next W pair (or Wp halves in last iter) ----
        {
            const char* __restrict__ n0 = (i3 < 2)
                ? ((const char*)Wqkv + (size_t)(h0 + 2) * 36864) : (const char*)Wp;
            const char* __restrict__ n1 = (i3 < 2)
                ? ((const char*)Wqkv + (size_t)(h1 + 2) * 36864) : ((const char*)Wp + 36864);
            #pragma unroll
            for (int i = 0; i < 4; ++i) {
                const int base = wv * 64 + i * 576;
                GLDS16(n0 + (size_t)(base + lane) * 16, smem + WB0 + base * 16);
            }
            #pragma unroll
            for (int i = 0; i < 4; ++i) {
                const int base = wv * 64 + i * 576;
                GLDS16(n1 + (size_t)(base + lane) * 16, smem + WB1 + base * 16);
            }
        }

        // ---- Q transposes: h0 -> chunk0, h1 -> chunk1 ----
        #pragma unroll
        for (int r = 0; r < 4; ++r) {
            const int row = lg * 4 + r;
            const int swz = (row & 6) << 3;
            *(bf16_t*)(pb + row * 64 + ((l15 * 2) ^ swz))             = q8a[r];
            *(bf16_t*)(pb + row * 64 + ((l15 * 2 + 32) ^ swz))        = q8a[4 + r];
            *(bf16_t*)(pb + 1024 + row * 64 + ((l15 * 2) ^ swz))      = q8b[r];
            *(bf16_t*)(pb + 1024 + row * 64 + ((l15 * 2 + 32) ^ swz)) = q8b[4 + r];
        }
        asm volatile("" ::: "memory");
        bf16x8 aq0 = *(const bf16x8*)(pb + l15 * 64 + ((lg * 16) ^ ((l15 & 6) << 3)));
        bf16x8 aq1 = *(const bf16x8*)(pb + 1024 + l15 * 64 + ((lg * 16) ^ ((l15 & 6) << 3)));
        asm volatile("" ::: "memory");

        // ---- fused S-loop: both heads per nt (2 indep streams) ----
        float sum0 = 0.f, sum1 = 0.f;
        f32x4 s1[9];
        #pragma unroll
        for (int nt = 0; nt < 9; ++nt) {
            const int krow = nt * 16 + l15;
            const int ksw = (lg * 16) ^ ((krow & 6) << 3);
            bf16x8 kf0 = *(const bf16x8*)(smem + K_BASE + krow * 64 + ksw);
            bf16x8 kf1 = *(const bf16x8*)(smem + K_BASE + 9216 + krow * 64 + ksw);
            f32x4 sv0 = MFMA16(kf0, aq0, fzero4());
            f32x4 sv1 = MFMA16(kf1, aq1, fzero4());
            bf16x4 b40 = *(const bf16x4*)(BIASf +
                         (size_t)((((h0 * 9 + wv) * 9 + nt) * 64 + lane) * 4));
            bf16x4 b41 = *(const bf16x4*)(BIASf +
                         (size_t)((((h1 * 9 + wv) * 9 + nt) * 64 + lane) * 4));
            bf16x4 pw;
            #pragma unroll
            for (int r = 0; r < 4; ++r) {
                float p = __builtin_amdgcn_exp2f(sv0[r] + (float)b40[r]);
                sum0 += p;
                pw[r] = (bf16_t)p;
                float q = __builtin_amdgcn_exp2f(sv1[r] + (float)b41[r]);
                sum1 += q;
                s1[nt][r] = q;
            }
            if (nt < 8)
                *(bf16x4*)(pb + (nt >> 1) * 1024 + l15 * 64 +
                           ((((nt & 1) << 5) + lg * 8) ^ pswz)) = pw;
            else
                *(bf16x4*)(pb + 4096 + l15 * 32 + lg * 8) = pw;
        }
        sum0 += __shfl_xor(sum0, 16, 64);
        sum0 += __shfl_xor(sum0, 32, 64);
        sum1 += __shfl_xor(sum1, 16, 64);
        sum1 += __shfl_xor(sum1, 32, 64);
        const float rinv0 = __builtin_amdgcn_rcpf(sum0);
        const float rinv1 = __builtin_amdgcn_rcpf(sum1);
        asm volatile("" ::: "memory");

        // ---- PV(h0) from strip ----
        f32x4 o00 = fzero4(), o01 = fzero4();
        __builtin_amdgcn_s_setprio(1);
        #pragma unroll
        for (int kt = 0; kt < 4; ++kt) {
            const int vs0 = ((l15 >> 2) & 3) << 4;
            bf16x8 ap  = *(const bf16x8*)(pb + kt * 1024 + l15 * 64 + ((lg * 16) ^ pswz));
            bf16x8 bv0 = *(const bf16x8*)(smem + VT_BASE + l15 * 288 + kt * 64 + ((lg * 16) ^ vs0));
            bf16x8 bv1 = *(const bf16x8*)(smem + VT_BASE + (16 + l15) * 288 + kt * 64 + ((lg * 16) ^ vs0));
            o00 = MFMA16(ap, bv0, o00);
            o01 = MFMA16(ap, bv1, o01);
        }
        {
            bf16x8 ap = bzero8(), bv0 = bzero8(), bv1 = bzero8();
            if (lg < 2) {
                ap  = *(const bf16x8*)(pb + 4096 + l15 * 32 + lg * 16);
                bv0 = *(const bf16x8*)(smem + VT_BASE + l15 * 288 + 256 + lg * 16);
                bv1 = *(const bf16x8*)(smem + VT_BASE + (16 + l15) * 288 + 256 + lg * 16);
            }
            o00 = MFMA16(ap, bv0, o00);
            o01 = MFMA16(ap, bv1, o01);
        }
        __builtin_amdgcn_s_setprio(0);
        asm volatile("" ::: "memory");

        // ---- P(h1) -> strip (after PV(h0) reads; in-wave DS order) ----
        #pragma unroll
        for (int nt = 0; nt < 9; ++nt) {
            bf16x4 pw;
            #pragma unroll
            for (int r = 0; r < 4; ++r) pw[r] = (bf16_t)s1[nt][r];
            if (nt < 8)
                *(bf16x4*)(pb + (nt >> 1) * 1024 + l15 * 64 +
                           ((((nt & 1) << 5) + lg * 8) ^ pswz)) = pw;
            else
                *(bf16x4*)(pb + 4096 + l15 * 32 + lg * 8) = pw;
        }
        asm volatile("" ::: "memory");

        // ---- PV(h1) from strip ----
        f32x4 o10 = fzero4(), o11 = fzero4();
        __builtin_amdgcn_s_setprio(1);
        #pragma unroll
        for (int kt = 0; kt < 4; ++kt) {
            const int vs0 = ((l15 >> 2) & 3) << 4;
            bf16x8 ap  = *(const bf16x8*)(pb + kt * 1024 + l15 * 64 + ((lg * 16) ^ pswz));
            bf16x8 bv0 = *(const bf16x8*)(smem + VT_BASE + 9216 + l15 * 288 + kt * 64 + ((lg * 16) ^ vs0));
            bf16x8 bv1 = *(const bf16x8*)(smem + VT_BASE + 9216 + (16 + l15) * 288 + kt * 64 + ((lg * 16) ^ vs0));
            o10 = MFMA16(ap, bv0, o10);
            o11 = MFMA16(ap, bv1, o11);
        }
        {
            bf16x8 ap = bzero8(), bv0 = bzero8(), bv1 = bzero8();
            if (lg < 2) {
                ap  = *(const bf16x8*)(pb + 4096 + l15 * 32 + lg * 16);
                bv0 = *(const bf16x8*)(smem + VT_BASE + 9216 + l15 * 288 + 256 + lg * 16);
                bv1 = *(const bf16x8*)(smem + VT_BASE + 9216 + (16 + l15) * 288 + 256 + lg * 16);
            }
            o10 = MFMA16(ap, bv0, o10);
            o11 = MFMA16(ap, bv1, o11);
        }
        __builtin_amdgcn_s_setprio(0);
        asm volatile("" ::: "memory");

        // ---- normalize + O transposes: h0 -> chunk0, h1 -> chunk1 ----
        #pragma unroll
        for (int r = 0; r < 4; ++r) {
            const float rq0 = __shfl(rinv0, lg * 4 + r, 16);
            const float rq1 = __shfl(rinv1, lg * 4 + r, 16);
            const int row = lg * 4 + r;
            const int swz = (row & 6) << 3;
            *(bf16_t*)(pb + row * 64 + ((l15 * 2) ^ swz))             = (bf16_t)(o00[r] * rq0);
            *(bf16_t*)(pb + row * 64 + ((l15 * 2 + 32) ^ swz))        = (bf16_t)(o01[r] * rq0);
            *(bf16_t*)(pb + 1024 + row * 64 + ((l15 * 2) ^ swz))      = (bf16_t)(o10[r] * rq1);
            *(bf16_t*)(pb + 1024 + row * 64 + ((l15 * 2 + 32) ^ swz)) = (bf16_t)(o11[r] * rq1);
        }
        asm volatile("" ::: "memory");
        ao[h0] = *(const bf16x8*)(pb + l15 * 64 + ((lg * 16) ^ ((l15 & 6) << 3)));
        ao[h1] = *(const bf16x8*)(pb + 1024 + l15 * 64 + ((lg * 16) ^ ((l15 & 6) << 3)));

        __syncthreads();              // BAR2: next W pair staged; K/Vt free
    }

    // ---- output projection (barrier-free): WB0 = Wp half0, WB1 = Wp half1 ----
    float* __restrict__ og = out + (size_t)win * 25920;
    #pragma unroll
    for (int half = 0; half < 2; ++half) {
        const int WH = half ? WB1 : WB0;
        f32x4 accp[6];
        #pragma unroll
        for (int nt = 0; nt < 6; ++nt) accp[nt] = fzero4();
        __builtin_amdgcn_s_setprio(1);
        #pragma unroll
        for (int kt = 0; kt < 6; ++kt) {
            #pragma unroll
            for (int nt = 0; nt < 6; ++nt) {
                bf16x8 bw = *(const bf16x8*)(smem + WH + ((kt * 6 + nt) * 64 + lane) * 16);
                accp[nt] = MFMA16(ao[kt], bw, accp[nt]);
            }
        }
        __builtin_amdgcn_s_setprio(0);
        #pragma unroll
        for (int nt = 0; nt < 6; ++nt) {
            const int col = half * 96 + nt * 16 + l15;
            if (col < 180) {
                const float bias = bp[col];
                #pragma unroll
                for (int r = 0; r < 4; ++r) {
                    const int row = wv * 16 + lg * 4 + r;
                    og[row * 180 + col] = accp[nt][r] + bias;
                }
            }
        }
    }
}

extern "C" void kernel_launch(void* const* d_in, const int* in_sizes, int n_in,
                              void* d_out, int out_size, void* d_ws, size_t ws_size,
                              hipStream_t stream) {
    const float* gs = (const float*)d_in[0];
    const float* wq = (const float*)d_in[1];
    const float* bq = (const float*)d_in[2];
    const float* wk = (const float*)d_in[3];
    const float* bk = (const float*)d_in[4];
    const float* wv = (const float*)d_in[5];
    const float* bv = (const float*)d_in[6];
    const float* wp = (const float*)d_in[7];
    const float* bp = (const float*)d_in[8];
    const float* bt = (const float*)d_in[9];

    char* ws = (char*)d_ws;
    bf16_t* Wqkv  = (bf16_t*)(ws);
    bf16_t* Wp    = (bf16_t*)(ws + 221184);
    bf16_t* BIASf = (bf16_t*)(ws + 294912);
    float*  bqkv  = (float*)(ws + 543744);

    pack_kernel<<<512, 256, 0, stream>>>(wq, bq, wk, bk, wv, bv, wp, bt,
                                         Wqkv, Wp, BIASf, bqkv);
    attn_kernel<<<2048, 576, 0, stream>>>(gs, Wqkv, Wp, BIASf, bqkv, bp, (float*)d_out);
}